// Round 6
// baseline (239.047 us; speedup 1.0000x reference)
//
#include <hip/hip_runtime.h>
#include <stdint.h>

#define Nn 16384
#define Dd 128
#define Qq 4096
#define Ee 256

typedef __bf16 bf16x8 __attribute__((ext_vector_type(8)));
typedef float floatx16 __attribute__((ext_vector_type(16)));

__device__ __forceinline__ float fexp2(float x) {
#if __has_builtin(__builtin_amdgcn_exp2f)
  return __builtin_amdgcn_exp2f(x);
#else
  return exp2f(x);
#endif
}
// pack two f32 -> bf16x2 (round-half-up, 3 VALU ops)
__device__ __forceinline__ unsigned pk_bf(float lo, float hi) {
  return __builtin_amdgcn_perm(__float_as_uint(hi) + 0x8000u,
                               __float_as_uint(lo) + 0x8000u, 0x07060302u);
}
__device__ __forceinline__ unsigned short bf1(float f) {
  return (unsigned short)((__float_as_uint(f) + 0x8000u) >> 16);
}
// async global->LDS, 16B per lane; lds dest = wave-uniform base + lane*16
__device__ __forceinline__ void stage16(const void* g, void* lds_uniform) {
  __builtin_amdgcn_global_load_lds(
      (const __attribute__((address_space(1))) unsigned int*)g,
      (__attribute__((address_space(3))) unsigned int*)lds_uniform, 16, 0, 0);
}

// ---- K1: LayerNorm -> tiled bf16 images + q/W cast -----------------------
// grid 512 = [b 2][tile 256 of 64 n-rows]; block 256.
// xn_t  per tile 16 KB: offset(kv,du) = (kv>>5)*8192+(du>>1)*1024+(du&1)*512+(kv&31)*16
// xnT_t per tile 16 KB: offset(d,kvu) = (d>>5)*4096+(kvu>>1)*1024+(kvu&1)*512+(d&31)*16
__global__ __launch_bounds__(256) void k_lnt(
    const float* __restrict__ x, const float* __restrict__ gamma,
    const float* __restrict__ beta, const float* __restrict__ queries,
    const float* __restrict__ W, char* __restrict__ xn_t,
    char* __restrict__ xnT_t, unsigned short* __restrict__ qb,
    unsigned short* __restrict__ wb) {
  __shared__ __align__(16) uint2 lds2[64 * 32];  // [kv][8B d-quad], pos m^(kv&31)
  const int tid = threadIdx.x;
  const int bid = blockIdx.x;
  const int b = bid >> 8, t = bid & 255;
  const int r = tid >> 2, qd = tid & 3;

  const float4* xp = (const float4*)(x + ((size_t)(b * Nn + t * 64 + r)) * Dd + qd * 32);
  float4 v[8];
  float s = 0.f, s2 = 0.f;
#pragma unroll
  for (int i = 0; i < 8; ++i) {
    v[i] = xp[i];
    s += (v[i].x + v[i].y) + (v[i].z + v[i].w);
    s2 += (v[i].x * v[i].x + v[i].y * v[i].y) + (v[i].z * v[i].z + v[i].w * v[i].w);
  }
  s += __shfl_xor(s, 1); s2 += __shfl_xor(s2, 1);
  s += __shfl_xor(s, 2); s2 += __shfl_xor(s2, 2);
  float mu = s * (1.0f / 128.0f);
  float var = s2 * (1.0f / 128.0f) - mu * mu;
  float rs = rsqrtf(var + 1e-5f);

  const float4* gp = (const float4*)(gamma + qd * 32);
  const float4* bp = (const float4*)(beta + qd * 32);
  const int rk = r & 31;
#pragma unroll
  for (int i = 0; i < 8; ++i) {
    float4 g = gp[i], bt = bp[i];
    unsigned lo = pk_bf((v[i].x - mu) * rs * g.x + bt.x, (v[i].y - mu) * rs * g.y + bt.y);
    unsigned hi = pk_bf((v[i].z - mu) * rs * g.z + bt.z, (v[i].w - mu) * rs * g.w + bt.w);
    lds2[r * 32 + ((qd * 8 + i) ^ rk)] = make_uint2(lo, hi);
  }
  __syncthreads();

  const size_t tb = ((size_t)(b * 256 + t)) * 16384;
#pragma unroll
  for (int p = 0; p < 4; ++p) {
    int u = p * 256 + tid;
    int kv = ((u >> 9) & 1) * 32 + (u & 31);
    int du = ((u >> 6) & 7) * 2 + ((u >> 5) & 1);
    uint2 a = lds2[kv * 32 + ((2 * du) ^ (kv & 31))];
    uint2 c = lds2[kv * 32 + ((2 * du + 1) ^ (kv & 31))];
    *(uint4*)(xn_t + tb + (size_t)u * 16) = make_uint4(a.x, a.y, c.x, c.y);
  }
  const int d = ((tid >> 6) << 5) + (tid & 31);
  const int klow = (tid >> 5) & 1;
  const int m0 = d >> 2;
  const unsigned sel = (d & 1) ? 0x07060302u : 0x05040100u;
#pragma unroll
  for (int e = 0; e < 4; ++e) {
    int kvu = 2 * e + klow;
    unsigned wv[8];
#pragma unroll
    for (int j = 0; j < 8; ++j) {
      int kv = kvu * 8 + j;
      uint2 uu = lds2[kv * 32 + (m0 ^ (kv & 31))];
      wv[j] = (d & 2) ? uu.y : uu.x;
    }
    uint4 o;
    o.x = __builtin_amdgcn_perm(wv[1], wv[0], sel);
    o.y = __builtin_amdgcn_perm(wv[3], wv[2], sel);
    o.z = __builtin_amdgcn_perm(wv[5], wv[4], sel);
    o.w = __builtin_amdgcn_perm(wv[7], wv[6], sel);
    *(uint4*)(xnT_t + tb + ((size_t)(tid >> 6)) * 4096 + e * 1024 + klow * 512 +
              (tid & 31) * 16) = o;
  }
  // cast queries (prescaled by SCALE*log2e) and W to bf16, vectorized
  const float QSC = 0.08838834764831845f * 1.4426950408889634f;
  const int total4 = (Qq * Dd + Ee * Dd) / 4;
  for (int u = bid * 256 + tid; u < total4; u += 512 * 256) {
    if (u < Qq * Dd / 4) {
      float4 v4 = ((const float4*)queries)[u];
      ((uint2*)qb)[u] = make_uint2(pk_bf(v4.x * QSC, v4.y * QSC),
                                   pk_bf(v4.z * QSC, v4.w * QSC));
    } else {
      float4 v4 = ((const float4*)W)[u - Qq * Dd / 4];
      ((uint2*)wb)[u - Qq * Dd / 4] =
          make_uint2(pk_bf(v4.x, v4.y), pk_bf(v4.z, v4.w));
    }
  }
}

// ---- K2: cross-attention, dbuf staging, P in registers -------------------
// grid 2*16*ns; block 256 = 4 waves x 64 q. LDS = 2 x (16K X + 16K Xt).
__global__ __launch_bounds__(256) void k_attn(
    const char* __restrict__ xn_t, const char* __restrict__ xnT_t,
    const unsigned short* __restrict__ qb,
    unsigned short* __restrict__ o_bf,       // [B][ns][Q][D] bf16
    float* __restrict__ l_part,              // [B][ns][Q]
    int ns_log2, int niter) {
  __shared__ __align__(16) char lds[65536];

  const int bid = blockIdx.x;
  const int ns = 1 << ns_log2;
  const int split = bid & (ns - 1);
  const int qt = (bid >> ns_log2) & 15;
  const int b = bid >> (ns_log2 + 4);
  const int tid = threadIdx.x;
  const int wave = tid >> 6, lane = tid & 63;
  const int col = lane & 31, half = lane >> 5;
  const int qwbase = qt * 256 + wave * 64;

  // Q B-fragments (prescaled bf16): frag[g*8+s], k = 16s+8h+j
  bf16x8 qf[16];
#pragma unroll
  for (int g = 0; g < 2; ++g)
#pragma unroll
    for (int s = 0; s < 8; ++s)
      qf[g * 8 + s] = *(const bf16x8*)(qb +
          (size_t)(qwbase + g * 32 + col) * Dd + s * 16 + half * 8);

  const floatx16 fz = {0.f,0.f,0.f,0.f,0.f,0.f,0.f,0.f,0.f,0.f,0.f,0.f,0.f,0.f,0.f,0.f};
  floatx16 O[8];
#pragma unroll
  for (int k = 0; k < 8; ++k) O[k] = fz;
  float ls0 = 0.f, ls1 = 0.f;

  const char* gx = xn_t + ((size_t)(b * 256 + split * niter)) * 16384;
  const char* gxt = xnT_t + ((size_t)(b * 256 + split * niter)) * 16384;

  // prologue stage into buf 0
  {
    const size_t ib = 0;
#pragma unroll
    for (int p = 0; p < 4; ++p) {
      int m = wave * 4 + p;
      stage16(gx + ib + m * 1024 + lane * 16, lds + m * 1024);
      stage16(gxt + ib + m * 1024 + lane * 16, lds + 16384 + m * 1024);
    }
  }

  for (int i = 0; i < niter; ++i) {
    __syncthreads();   // buf[i&1] ready (vmcnt drained; loads flew during compute)
    if (i + 1 < niter) {
      char* nb = lds + ((i + 1) & 1) * 32768;
      const size_t ib = (size_t)(i + 1) * 16384;
#pragma unroll
      for (int p = 0; p < 4; ++p) {
        int m = wave * 4 + p;
        stage16(gx + ib + m * 1024 + lane * 16, nb + m * 1024);
        stage16(gxt + ib + m * 1024 + lane * 16, nb + 16384 + m * 1024);
      }
    }
    const char* ax_base = lds + (i & 1) * 32768;
    const char* bx_base = ax_base + 16384;

#pragma unroll
    for (int kb = 0; kb < 2; ++kb) {
      // S^T[32 kv][64 q] for this kv-halftile
      floatx16 S0 = fz, S1 = fz;
#pragma unroll
      for (int s = 0; s < 8; ++s) {
        bf16x8 ax = *(const bf16x8*)(ax_base + kb * 8192 + s * 1024 + half * 512 + col * 16);
        S0 = __builtin_amdgcn_mfma_f32_32x32x16_bf16(ax, qf[s], S0, 0, 0, 0);
        S1 = __builtin_amdgcn_mfma_f32_32x32x16_bf16(ax, qf[8 + s], S1, 0, 0, 0);
      }
      // exp2 + l-sum + pack kv-pairs (C rows r=2t,2t+1 are adjacent kv)
      unsigned og0[8], og1[8], pg0[8], pg1[8];
#pragma unroll
      for (int t = 0; t < 8; ++t) {
        float e0 = fexp2(S0[2 * t]), e1 = fexp2(S0[2 * t + 1]);
        float e2 = fexp2(S1[2 * t]), e3 = fexp2(S1[2 * t + 1]);
        ls0 += e0 + e1; ls1 += e2 + e3;
        og0[t] = pk_bf(e0, e1);
        og1[t] = pk_bf(e2, e3);
      }
      // cross-half exchange: C-layout rows sit at +4*half, A-layout k at +8*half
#pragma unroll
      for (int t = 0; t < 8; ++t) {
        pg0[t] = (unsigned)__shfl_xor((int)og0[t], 32);
        pg1[t] = (unsigned)__shfl_xor((int)og1[t], 32);
      }
#pragma unroll
      for (int s2l = 0; s2l < 2; ++s2l) {
        const int i0 = 4 * s2l + 2 * half;
        uint4 f0u = half ? make_uint4(pg0[i0], pg0[i0 + 1], og0[i0], og0[i0 + 1])
                         : make_uint4(og0[i0], og0[i0 + 1], pg0[i0], pg0[i0 + 1]);
        uint4 f1u = half ? make_uint4(pg1[i0], pg1[i0 + 1], og1[i0], og1[i0 + 1])
                         : make_uint4(og1[i0], og1[i0 + 1], pg1[i0], pg1[i0 + 1]);
        const int s2 = 2 * kb + s2l;
#pragma unroll
        for (int dn = 0; dn < 4; ++dn) {
          bf16x8 bx = *(const bf16x8*)(bx_base + dn * 4096 + s2 * 1024 + half * 512 + col * 16);
          O[dn] = __builtin_amdgcn_mfma_f32_32x32x16_bf16(*(bf16x8*)&f0u, bx, O[dn], 0, 0, 0);
          O[4 + dn] = __builtin_amdgcn_mfma_f32_32x32x16_bf16(*(bf16x8*)&f1u, bx, O[4 + dn], 0, 0, 0);
        }
      }
    }
  }

  // epilogue
  float lt0 = ls0 + __shfl_xor(ls0, 32);
  float lt1 = ls1 + __shfl_xor(ls1, 32);
  if (half == 0) {
    size_t lb = ((size_t)(b * ns + split)) * Qq + qwbase;
    l_part[lb + col] = lt0;
    l_part[lb + 32 + col] = lt1;
  }
  unsigned short* ob = o_bf + (((size_t)(b * ns + split)) * Qq + qwbase) * Dd;
#pragma unroll
  for (int g = 0; g < 2; ++g)
#pragma unroll
    for (int dn = 0; dn < 4; ++dn)
#pragma unroll
      for (int r = 0; r < 16; ++r) {
        int q = g * 32 + (r & 3) + 8 * (r >> 2) + 4 * half;
        ob[(size_t)q * Dd + dn * 32 + col] = bf1(O[g * 4 + dn][r]);
      }
}

// ---- K3: combine bf16 splits, normalize, trailing GEMM -------------------
// grid 256 = [b 2][qchunk 128 of 32 q]; block 256 = 4 waves (wave owns 64 E)
__global__ __launch_bounds__(256) void k_comb(
    const unsigned short* __restrict__ o_bf, const float* __restrict__ l_part,
    const unsigned short* __restrict__ wb, float* __restrict__ out, int ns) {
  __shared__ __align__(16) char lds_a[8192];   // [32 q][16 du], q^(du&7) swizzle
  __shared__ float lds_linv[32];
  const int bid = blockIdx.x;
  const int b = bid >> 7, qc = bid & 127;
  const int qbase = qc * 32;
  const int tid = threadIdx.x;
  const int wave = tid >> 6, lane = tid & 63;
  const int col = lane & 31, half = lane >> 5;

  if (tid < 32) {
    float l = 0.f;
    for (int s = 0; s < ns; ++s)
      l += l_part[(size_t)(b * ns + s) * Qq + qbase + tid];
    lds_linv[tid] = 1.0f / l;
  }
  __syncthreads();

#pragma unroll
  for (int i = 0; i < 4; ++i) {
    int idx = i * 256 + tid;      // 1024 units of 4 d: q = idx>>5, d4 = idx&31
    int q = idx >> 5, d4 = idx & 31;
    float a0 = 0.f, a1 = 0.f, a2 = 0.f, a3 = 0.f;
    for (int s = 0; s < ns; ++s) {
      uint2 v = *(const uint2*)(o_bf +
          ((size_t)(b * ns + s) * Qq + qbase + q) * Dd + d4 * 4);
      a0 += __uint_as_float(v.x << 16);
      a1 += __uint_as_float(v.x & 0xffff0000u);
      a2 += __uint_as_float(v.y << 16);
      a3 += __uint_as_float(v.y & 0xffff0000u);
    }
    float li = lds_linv[q];
    int du = d4 >> 1;
    int pos = (du >> 1) * 1024 + (du & 1) * 512 + ((q ^ (du & 7)) & 31) * 16 + (d4 & 1) * 8;
    *(uint2*)(lds_a + pos) =
        make_uint2(pk_bf(a0 * li, a1 * li), pk_bf(a2 * li, a3 * li));
  }
  __syncthreads();

  bf16x8 af[8];
#pragma unroll
  for (int s = 0; s < 8; ++s) {
    int du = 2 * s + half;
    af[s] = *(const bf16x8*)(lds_a + s * 1024 + half * 512 + ((col ^ (du & 7)) & 31) * 16);
  }

  const floatx16 fz = {0.f,0.f,0.f,0.f,0.f,0.f,0.f,0.f,0.f,0.f,0.f,0.f,0.f,0.f,0.f,0.f};
#pragma unroll
  for (int et = 0; et < 2; ++et) {
    floatx16 C = fz;
    int e_row = wave * 64 + et * 32 + col;
#pragma unroll
    for (int s = 0; s < 8; ++s) {
      bf16x8 bw = *(const bf16x8*)(wb + (size_t)e_row * Dd + s * 16 + half * 8);
      C = __builtin_amdgcn_mfma_f32_32x32x16_bf16(af[s], bw, C, 0, 0, 0);
    }
#pragma unroll
    for (int r = 0; r < 16; ++r) {
      int q = qbase + (r & 3) + 8 * (r >> 2) + 4 * half;
      out[((size_t)b * Qq + q) * Ee + wave * 64 + et * 32 + col] = C[r];
    }
  }
}

// ---- launcher ------------------------------------------------------------
extern "C" void kernel_launch(void* const* d_in, const int* in_sizes, int n_in,
                              void* d_out, int out_size, void* d_ws, size_t ws_size,
                              hipStream_t stream) {
  const float* x = (const float*)d_in[0];
  const float* gamma = (const float*)d_in[1];
  const float* beta = (const float*)d_in[2];
  const float* queries = (const float*)d_in[3];
  const float* W = (const float*)d_in[4];
  float* out = (float*)d_out;

  char* w = (char*)d_ws;
  char* xn_t = w;                                     // 8 MB
  char* xnT_t = w + 8388608;                          // 8 MB
  unsigned short* qb = (unsigned short*)(w + 16777216);   // 1 MB
  unsigned short* wb = (unsigned short*)(w + 17825792);   // 64 KB
  unsigned short* o_bf = (unsigned short*)(w + 17891328); // 2*ns*Q*D*2

  const size_t base = 17891328;
  const size_t need16 = base + (size_t)2 * 16 * Qq * Dd * 2 + (size_t)2 * 16 * Qq * 4;
  int ns_log2 = (ws_size >= need16) ? 4 : 3;
  int ns = 1 << ns_log2;
  int niter = 256 / ns;
  float* l_part = (float*)(w + base + (size_t)2 * ns * Qq * Dd * 2);

  k_lnt<<<dim3(512), dim3(256), 0, stream>>>(x, gamma, beta, queries, W,
                                             xn_t, xnT_t, qb, wb);
  k_attn<<<dim3(2 * 16 * ns), dim3(256), 0, stream>>>(xn_t, xnT_t, qb,
                                                      o_bf, l_part, ns_log2, niter);
  k_comb<<<dim3(256), dim3(256), 0, stream>>>(o_bf, l_part, wb, out, ns);
}

// Round 7
// 205.729 us; speedup vs baseline: 1.1620x; 1.1620x over previous
//
#include <hip/hip_runtime.h>
#include <stdint.h>

#define Nn 16384
#define Dd 128
#define Qq 4096
#define Ee 256

typedef __bf16 bf16x8 __attribute__((ext_vector_type(8)));
typedef float floatx16 __attribute__((ext_vector_type(16)));

__device__ __forceinline__ float fexp2(float x) {
#if __has_builtin(__builtin_amdgcn_exp2f)
  return __builtin_amdgcn_exp2f(x);
#else
  return exp2f(x);
#endif
}
// pack two f32 -> bf16x2 (round-half-up, 3 VALU ops)
__device__ __forceinline__ unsigned pk_bf(float lo, float hi) {
  return __builtin_amdgcn_perm(__float_as_uint(hi) + 0x8000u,
                               __float_as_uint(lo) + 0x8000u, 0x07060302u);
}
__device__ __forceinline__ unsigned short bf1(float f) {
  return (unsigned short)((__float_as_uint(f) + 0x8000u) >> 16);
}
// async global->LDS, 16B per lane; lds dest = wave-uniform base + lane*16
__device__ __forceinline__ void stage16(const void* g, void* lds_uniform) {
  __builtin_amdgcn_global_load_lds(
      (const __attribute__((address_space(1))) unsigned int*)g,
      (__attribute__((address_space(3))) unsigned int*)lds_uniform, 16, 0, 0);
}

// ---- K1: LayerNorm -> tiled bf16 images + q/W cast -----------------------
// grid 512 = [b 2][tile 256 of 64 n-rows]; block 256.
// xn_t  per tile 16 KB: offset(kv,du) = (kv>>5)*8192+(du>>1)*1024+(du&1)*512+(kv&31)*16
// xnT_t per tile 16 KB: offset(d,kvu) = (d>>5)*4096+(kvu>>1)*1024+(kvu&1)*512+(d&31)*16
__global__ __launch_bounds__(256) void k_lnt(
    const float* __restrict__ x, const float* __restrict__ gamma,
    const float* __restrict__ beta, const float* __restrict__ queries,
    const float* __restrict__ W, char* __restrict__ xn_t,
    char* __restrict__ xnT_t, unsigned short* __restrict__ qb,
    unsigned short* __restrict__ wb) {
  __shared__ __align__(16) uint2 lds2[64 * 32];  // [kv][8B d-quad], pos m^(kv&31)
  const int tid = threadIdx.x;
  const int bid = blockIdx.x;
  const int b = bid >> 8, t = bid & 255;
  const int r = tid >> 2, qd = tid & 3;

  const float4* xp = (const float4*)(x + ((size_t)(b * Nn + t * 64 + r)) * Dd + qd * 32);
  float4 v[8];
  float s = 0.f, s2 = 0.f;
#pragma unroll
  for (int i = 0; i < 8; ++i) {
    v[i] = xp[i];
    s += (v[i].x + v[i].y) + (v[i].z + v[i].w);
    s2 += (v[i].x * v[i].x + v[i].y * v[i].y) + (v[i].z * v[i].z + v[i].w * v[i].w);
  }
  s += __shfl_xor(s, 1); s2 += __shfl_xor(s2, 1);
  s += __shfl_xor(s, 2); s2 += __shfl_xor(s2, 2);
  float mu = s * (1.0f / 128.0f);
  float var = s2 * (1.0f / 128.0f) - mu * mu;
  float rs = rsqrtf(var + 1e-5f);

  const float4* gp = (const float4*)(gamma + qd * 32);
  const float4* bp = (const float4*)(beta + qd * 32);
  const int rk = r & 31;
#pragma unroll
  for (int i = 0; i < 8; ++i) {
    float4 g = gp[i], bt = bp[i];
    unsigned lo = pk_bf((v[i].x - mu) * rs * g.x + bt.x, (v[i].y - mu) * rs * g.y + bt.y);
    unsigned hi = pk_bf((v[i].z - mu) * rs * g.z + bt.z, (v[i].w - mu) * rs * g.w + bt.w);
    lds2[r * 32 + ((qd * 8 + i) ^ rk)] = make_uint2(lo, hi);
  }
  __syncthreads();

  const size_t tb = ((size_t)(b * 256 + t)) * 16384;
#pragma unroll
  for (int p = 0; p < 4; ++p) {
    int u = p * 256 + tid;
    int kv = ((u >> 9) & 1) * 32 + (u & 31);
    int du = ((u >> 6) & 7) * 2 + ((u >> 5) & 1);
    uint2 a = lds2[kv * 32 + ((2 * du) ^ (kv & 31))];
    uint2 c = lds2[kv * 32 + ((2 * du + 1) ^ (kv & 31))];
    *(uint4*)(xn_t + tb + (size_t)u * 16) = make_uint4(a.x, a.y, c.x, c.y);
  }
  const int d = ((tid >> 6) << 5) + (tid & 31);
  const int klow = (tid >> 5) & 1;
  const int m0 = d >> 2;
  const unsigned sel = (d & 1) ? 0x07060302u : 0x05040100u;
#pragma unroll
  for (int e = 0; e < 4; ++e) {
    int kvu = 2 * e + klow;
    unsigned wv[8];
#pragma unroll
    for (int j = 0; j < 8; ++j) {
      int kv = kvu * 8 + j;
      uint2 uu = lds2[kv * 32 + (m0 ^ (kv & 31))];
      wv[j] = (d & 2) ? uu.y : uu.x;
    }
    uint4 o;
    o.x = __builtin_amdgcn_perm(wv[1], wv[0], sel);
    o.y = __builtin_amdgcn_perm(wv[3], wv[2], sel);
    o.z = __builtin_amdgcn_perm(wv[5], wv[4], sel);
    o.w = __builtin_amdgcn_perm(wv[7], wv[6], sel);
    *(uint4*)(xnT_t + tb + ((size_t)(tid >> 6)) * 4096 + e * 1024 + klow * 512 +
              (tid & 31) * 16) = o;
  }
  // cast queries (prescaled by SCALE*log2e) and W to bf16, vectorized
  const float QSC = 0.08838834764831845f * 1.4426950408889634f;
  const int total4 = (Qq * Dd + Ee * Dd) / 4;
  for (int u = bid * 256 + tid; u < total4; u += 512 * 256) {
    if (u < Qq * Dd / 4) {
      float4 v4 = ((const float4*)queries)[u];
      ((uint2*)qb)[u] = make_uint2(pk_bf(v4.x * QSC, v4.y * QSC),
                                   pk_bf(v4.z * QSC, v4.w * QSC));
    } else {
      float4 v4 = ((const float4*)W)[u - Qq * Dd / 4];
      ((uint2*)wb)[u - Qq * Dd / 4] =
          make_uint2(pk_bf(v4.x, v4.y), pk_bf(v4.z, v4.w));
    }
  }
}

// ---- K2: cross-attention, 64 q/wave, P via per-wave LDS (kb-reuse) -------
// grid 2*16*ns; block 256 = 4 waves x 64 q (2 groups of 32).
// LDS 48 KB = 16K X + 16K Xt + 4 waves x 4 KB P.  Arch VGPR ~128 + 128 acc
// -> 2 blocks/CU (the R5-proven budget).  All DS accesses base+lane*{8,16}.
__global__ __launch_bounds__(256) void k_attn(
    const char* __restrict__ xn_t, const char* __restrict__ xnT_t,
    const unsigned short* __restrict__ qb,
    unsigned short* __restrict__ o_bf,       // [B][ns][Q][D] bf16
    float* __restrict__ l_part,              // [B][ns][Q]
    int ns_log2, int niter) {
  __shared__ __align__(16) char lds[49152];
  char* lds_x = lds;            // 16 KB X tile
  char* lds_xt = lds + 16384;   // 16 KB Xt tile
  char* lds_p = lds + 32768;    // 16 KB: per-wave 4 KB = [2 g][4 kvu][32 q][16B]

  const int bid = blockIdx.x;
  const int ns = 1 << ns_log2;
  const int split = bid & (ns - 1);
  const int qt = (bid >> ns_log2) & 15;
  const int b = bid >> (ns_log2 + 4);
  const int tid = threadIdx.x;
  const int wave = tid >> 6, lane = tid & 63;
  const int col = lane & 31, half = lane >> 5;
  const int qwbase = qt * 256 + wave * 64;

  // Q B-fragments (prescaled bf16): frag[g*8+s], k = 16s+8h+j, n = g*32+col
  bf16x8 qf[16];
#pragma unroll
  for (int g = 0; g < 2; ++g)
#pragma unroll
    for (int s = 0; s < 8; ++s)
      qf[g * 8 + s] = *(const bf16x8*)(qb +
          (size_t)(qwbase + g * 32 + col) * Dd + s * 16 + half * 8);

  const floatx16 fz = {0.f,0.f,0.f,0.f,0.f,0.f,0.f,0.f,0.f,0.f,0.f,0.f,0.f,0.f,0.f,0.f};
  floatx16 O[8];
#pragma unroll
  for (int k = 0; k < 8; ++k) O[k] = fz;
  float ls0 = 0.f, ls1 = 0.f;

  const char* gx = xn_t + ((size_t)(b * 256 + split * niter)) * 16384;
  const char* gxt = xnT_t + ((size_t)(b * 256 + split * niter)) * 16384;
  char* pw = lds_p + wave * 4096;

  for (int i = 0; i < niter; ++i) {
    const size_t ib = (size_t)i * 16384;
#pragma unroll
    for (int p = 0; p < 4; ++p) {
      int m = wave * 4 + p;
      stage16(gx + ib + m * 1024 + lane * 16, lds_x + m * 1024);
      stage16(gxt + ib + m * 1024 + lane * 16, lds_xt + m * 1024);
    }
    __syncthreads();

#pragma unroll
    for (int kb = 0; kb < 2; ++kb) {
      // S^T[32 kv][64 q] for this kv-half; ax shared by both q-groups
      floatx16 S0 = fz, S1 = fz;
#pragma unroll
      for (int s = 0; s < 8; ++s) {
        bf16x8 ax = *(const bf16x8*)(lds_x + kb * 8192 + s * 1024 + half * 512 + col * 16);
        S0 = __builtin_amdgcn_mfma_f32_32x32x16_bf16(ax, qf[s], S0, 0, 0, 0);
        S1 = __builtin_amdgcn_mfma_f32_32x32x16_bf16(ax, qf[8 + s], S1, 0, 0, 0);
      }
      // exp2 + l-sum; write P to per-wave LDS (in-wave DS order, no barrier)
      // reg 4t+e holds kv = 8t + 4*half + e  -> uint2 covers kv 8t+4h..+3
#pragma unroll
      for (int t = 0; t < 4; ++t) {
        float a0 = fexp2(S0[4 * t]), a1 = fexp2(S0[4 * t + 1]);
        float a2 = fexp2(S0[4 * t + 2]), a3 = fexp2(S0[4 * t + 3]);
        float b0 = fexp2(S1[4 * t]), b1 = fexp2(S1[4 * t + 1]);
        float b2 = fexp2(S1[4 * t + 2]), b3 = fexp2(S1[4 * t + 3]);
        ls0 += (a0 + a1) + (a2 + a3);
        ls1 += (b0 + b1) + (b2 + b3);
        int ofs = t * 512 + col * 16 + half * 8;   // slab kvu=t, row q=col
        *(uint2*)(pw + ofs) = make_uint2(pk_bf(a0, a1), pk_bf(a2, a3));
        *(uint2*)(pw + 2048 + ofs) = make_uint2(pk_bf(b0, b1), pk_bf(b2, b3));
      }
      // O[64 q][128 d] += P . Xt ; bx shared across q-groups
#pragma unroll
      for (int s2l = 0; s2l < 2; ++s2l) {
        bf16x8 ap0 = *(const bf16x8*)(pw + s2l * 1024 + half * 512 + col * 16);
        bf16x8 ap1 = *(const bf16x8*)(pw + 2048 + s2l * 1024 + half * 512 + col * 16);
        const int s2 = 2 * kb + s2l;
#pragma unroll
        for (int dn = 0; dn < 4; ++dn) {
          bf16x8 bx = *(const bf16x8*)(lds_xt + dn * 4096 + s2 * 1024 + half * 512 + col * 16);
          O[dn] = __builtin_amdgcn_mfma_f32_32x32x16_bf16(ap0, bx, O[dn], 0, 0, 0);
          O[4 + dn] = __builtin_amdgcn_mfma_f32_32x32x16_bf16(ap1, bx, O[4 + dn], 0, 0, 0);
        }
      }
    }
    __syncthreads();
  }

  // epilogue
  float lt0 = ls0 + __shfl_xor(ls0, 32);
  float lt1 = ls1 + __shfl_xor(ls1, 32);
  if (half == 0) {
    size_t lb = ((size_t)(b * ns + split)) * Qq + qwbase;
    l_part[lb + col] = lt0;
    l_part[lb + 32 + col] = lt1;
  }
  unsigned short* ob = o_bf + (((size_t)(b * ns + split)) * Qq + qwbase) * Dd;
#pragma unroll
  for (int g = 0; g < 2; ++g)
#pragma unroll
    for (int dn = 0; dn < 4; ++dn)
#pragma unroll
      for (int r = 0; r < 16; ++r) {
        int q = g * 32 + (r & 3) + 8 * (r >> 2) + 4 * half;
        ob[(size_t)q * Dd + dn * 32 + col] = bf1(O[g * 4 + dn][r]);
      }
}

// ---- K3: combine bf16 splits, normalize, trailing GEMM -------------------
// grid 256 = [b 2][qchunk 128 of 32 q]; block 256 = 4 waves (wave owns 64 E)
__global__ __launch_bounds__(256) void k_comb(
    const unsigned short* __restrict__ o_bf, const float* __restrict__ l_part,
    const unsigned short* __restrict__ wb, float* __restrict__ out, int ns) {
  __shared__ __align__(16) char lds_a[8192];   // [32 q][16 du], q^(du&7) swizzle
  __shared__ float lds_linv[32];
  const int bid = blockIdx.x;
  const int b = bid >> 7, qc = bid & 127;
  const int qbase = qc * 32;
  const int tid = threadIdx.x;
  const int wave = tid >> 6, lane = tid & 63;
  const int col = lane & 31, half = lane >> 5;

  if (tid < 32) {
    float l = 0.f;
    for (int s = 0; s < ns; ++s)
      l += l_part[(size_t)(b * ns + s) * Qq + qbase + tid];
    lds_linv[tid] = 1.0f / l;
  }
  __syncthreads();

#pragma unroll
  for (int i = 0; i < 4; ++i) {
    int idx = i * 256 + tid;      // 1024 units of 4 d: q = idx>>5, d4 = idx&31
    int q = idx >> 5, d4 = idx & 31;
    float a0 = 0.f, a1 = 0.f, a2 = 0.f, a3 = 0.f;
    for (int s = 0; s < ns; ++s) {
      uint2 v = *(const uint2*)(o_bf +
          ((size_t)(b * ns + s) * Qq + qbase + q) * Dd + d4 * 4);
      a0 += __uint_as_float(v.x << 16);
      a1 += __uint_as_float(v.x & 0xffff0000u);
      a2 += __uint_as_float(v.y << 16);
      a3 += __uint_as_float(v.y & 0xffff0000u);
    }
    float li = lds_linv[q];
    int du = d4 >> 1;
    int pos = (du >> 1) * 1024 + (du & 1) * 512 + ((q ^ (du & 7)) & 31) * 16 + (d4 & 1) * 8;
    *(uint2*)(lds_a + pos) =
        make_uint2(pk_bf(a0 * li, a1 * li), pk_bf(a2 * li, a3 * li));
  }
  __syncthreads();

  bf16x8 af[8];
#pragma unroll
  for (int s = 0; s < 8; ++s) {
    int du = 2 * s + half;
    af[s] = *(const bf16x8*)(lds_a + s * 1024 + half * 512 + ((col ^ (du & 7)) & 31) * 16);
  }

  const floatx16 fz = {0.f,0.f,0.f,0.f,0.f,0.f,0.f,0.f,0.f,0.f,0.f,0.f,0.f,0.f,0.f,0.f};
#pragma unroll
  for (int et = 0; et < 2; ++et) {
    floatx16 C = fz;
    int e_row = wave * 64 + et * 32 + col;
#pragma unroll
    for (int s = 0; s < 8; ++s) {
      bf16x8 bw = *(const bf16x8*)(wb + (size_t)e_row * Dd + s * 16 + half * 8);
      C = __builtin_amdgcn_mfma_f32_32x32x16_bf16(af[s], bw, C, 0, 0, 0);
    }
#pragma unroll
    for (int r = 0; r < 16; ++r) {
      int q = qbase + (r & 3) + 8 * (r >> 2) + 4 * half;
      out[((size_t)b * Qq + q) * Ee + wave * 64 + et * 32 + col] = C[r];
    }
  }
}

// ---- launcher ------------------------------------------------------------
extern "C" void kernel_launch(void* const* d_in, const int* in_sizes, int n_in,
                              void* d_out, int out_size, void* d_ws, size_t ws_size,
                              hipStream_t stream) {
  const float* x = (const float*)d_in[0];
  const float* gamma = (const float*)d_in[1];
  const float* beta = (const float*)d_in[2];
  const float* queries = (const float*)d_in[3];
  const float* W = (const float*)d_in[4];
  float* out = (float*)d_out;

  char* w = (char*)d_ws;
  char* xn_t = w;                                     // 8 MB
  char* xnT_t = w + 8388608;                          // 8 MB
  unsigned short* qb = (unsigned short*)(w + 16777216);   // 1 MB
  unsigned short* wb = (unsigned short*)(w + 17825792);   // 64 KB
  unsigned short* o_bf = (unsigned short*)(w + 17891328); // 2*ns*Q*D*2

  const size_t base = 17891328;
  const size_t need16 = base + (size_t)2 * 16 * Qq * Dd * 2 + (size_t)2 * 16 * Qq * 4;
  int ns_log2 = (ws_size >= need16) ? 4 : 3;
  int ns = 1 << ns_log2;
  int niter = 256 / ns;
  float* l_part = (float*)(w + base + (size_t)2 * ns * Qq * Dd * 2);

  k_lnt<<<dim3(512), dim3(256), 0, stream>>>(x, gamma, beta, queries, W,
                                             xn_t, xnT_t, qb, wb);
  k_attn<<<dim3(2 * 16 * ns), dim3(256), 0, stream>>>(xn_t, xnT_t, qb,
                                                      o_bf, l_part, ns_log2, niter);
  k_comb<<<dim3(256), dim3(256), 0, stream>>>(o_bf, l_part, wb, out, ns);
}

// Round 8
// 202.361 us; speedup vs baseline: 1.1813x; 1.0166x over previous
//
#include <hip/hip_runtime.h>
#include <stdint.h>

#define Nn 16384
#define Dd 128
#define Qq 4096
#define Ee 256

typedef __bf16 bf16x8 __attribute__((ext_vector_type(8)));
typedef float floatx16 __attribute__((ext_vector_type(16)));

__device__ __forceinline__ float fexp2(float x) {
#if __has_builtin(__builtin_amdgcn_exp2f)
  return __builtin_amdgcn_exp2f(x);
#else
  return exp2f(x);
#endif
}
// pack two f32 -> bf16x2 (round-half-up, 3 VALU ops)
__device__ __forceinline__ unsigned pk_bf(float lo, float hi) {
  return __builtin_amdgcn_perm(__float_as_uint(hi) + 0x8000u,
                               __float_as_uint(lo) + 0x8000u, 0x07060302u);
}
__device__ __forceinline__ unsigned short bf1(float f) {
  return (unsigned short)((__float_as_uint(f) + 0x8000u) >> 16);
}
// async global->LDS; lds dest = wave-uniform base, HW adds lane*16
__device__ __forceinline__ void stage16(const void* g, void* lds_uniform) {
  __builtin_amdgcn_global_load_lds(
      (const __attribute__((address_space(1))) unsigned int*)g,
      (__attribute__((address_space(3))) unsigned int*)lds_uniform, 16, 0, 0);
}

// ---- K1: LayerNorm -> tiled bf16 images + q/W cast -----------------------
// grid 512 = [b 2][tile 256 of 64 n-rows]; block 256.
// xn_t  per tile 16 KB: offset(kv,du) = (kv>>5)*8192+(du>>1)*1024+(du&1)*512+(kv&31)*16
// xnT_t per tile 16 KB: offset(d,kvu) = (d>>5)*4096+(kvu>>1)*1024+(kvu&1)*512+(d&31)*16
__global__ __launch_bounds__(256) void k_lnt(
    const float* __restrict__ x, const float* __restrict__ gamma,
    const float* __restrict__ beta, const float* __restrict__ queries,
    const float* __restrict__ W, char* __restrict__ xn_t,
    char* __restrict__ xnT_t, unsigned short* __restrict__ qb,
    unsigned short* __restrict__ wb) {
  __shared__ __align__(16) uint2 lds2[64 * 32];  // [kv][8B d-quad], pos m^(kv&31)
  const int tid = threadIdx.x;
  const int bid = blockIdx.x;
  const int b = bid >> 8, t = bid & 255;
  const int r = tid >> 2, qd = tid & 3;

  const float4* xp = (const float4*)(x + ((size_t)(b * Nn + t * 64 + r)) * Dd + qd * 32);
  float4 v[8];
  float s = 0.f, s2 = 0.f;
#pragma unroll
  for (int i = 0; i < 8; ++i) {
    v[i] = xp[i];
    s += (v[i].x + v[i].y) + (v[i].z + v[i].w);
    s2 += (v[i].x * v[i].x + v[i].y * v[i].y) + (v[i].z * v[i].z + v[i].w * v[i].w);
  }
  s += __shfl_xor(s, 1); s2 += __shfl_xor(s2, 1);
  s += __shfl_xor(s, 2); s2 += __shfl_xor(s2, 2);
  float mu = s * (1.0f / 128.0f);
  float var = s2 * (1.0f / 128.0f) - mu * mu;
  float rs = rsqrtf(var + 1e-5f);

  const float4* gp = (const float4*)(gamma + qd * 32);
  const float4* bp = (const float4*)(beta + qd * 32);
  const int rk = r & 31;
#pragma unroll
  for (int i = 0; i < 8; ++i) {
    float4 g = gp[i], bt = bp[i];
    unsigned lo = pk_bf((v[i].x - mu) * rs * g.x + bt.x, (v[i].y - mu) * rs * g.y + bt.y);
    unsigned hi = pk_bf((v[i].z - mu) * rs * g.z + bt.z, (v[i].w - mu) * rs * g.w + bt.w);
    lds2[r * 32 + ((qd * 8 + i) ^ rk)] = make_uint2(lo, hi);
  }
  __syncthreads();

  const size_t tb = ((size_t)(b * 256 + t)) * 16384;
#pragma unroll
  for (int p = 0; p < 4; ++p) {
    int u = p * 256 + tid;
    int kv = ((u >> 9) & 1) * 32 + (u & 31);
    int du = ((u >> 6) & 7) * 2 + ((u >> 5) & 1);
    uint2 a = lds2[kv * 32 + ((2 * du) ^ (kv & 31))];
    uint2 c = lds2[kv * 32 + ((2 * du + 1) ^ (kv & 31))];
    *(uint4*)(xn_t + tb + (size_t)u * 16) = make_uint4(a.x, a.y, c.x, c.y);
  }
  const int d = ((tid >> 6) << 5) + (tid & 31);
  const int klow = (tid >> 5) & 1;
  const int m0 = d >> 2;
  const unsigned sel = (d & 1) ? 0x07060302u : 0x05040100u;
#pragma unroll
  for (int e = 0; e < 4; ++e) {
    int kvu = 2 * e + klow;
    unsigned wv[8];
#pragma unroll
    for (int j = 0; j < 8; ++j) {
      int kv = kvu * 8 + j;
      uint2 uu = lds2[kv * 32 + (m0 ^ (kv & 31))];
      wv[j] = (d & 2) ? uu.y : uu.x;
    }
    uint4 o;
    o.x = __builtin_amdgcn_perm(wv[1], wv[0], sel);
    o.y = __builtin_amdgcn_perm(wv[3], wv[2], sel);
    o.z = __builtin_amdgcn_perm(wv[5], wv[4], sel);
    o.w = __builtin_amdgcn_perm(wv[7], wv[6], sel);
    *(uint4*)(xnT_t + tb + ((size_t)(tid >> 6)) * 4096 + e * 1024 + klow * 512 +
              (tid & 31) * 16) = o;
  }
  // cast queries (prescaled by SCALE*log2e) and W to bf16, vectorized
  const float QSC = 0.08838834764831845f * 1.4426950408889634f;
  const int total4 = (Qq * Dd + Ee * Dd) / 4;
  for (int u = bid * 256 + tid; u < total4; u += 512 * 256) {
    if (u < Qq * Dd / 4) {
      float4 v4 = ((const float4*)queries)[u];
      ((uint2*)qb)[u] = make_uint2(pk_bf(v4.x * QSC, v4.y * QSC),
                                   pk_bf(v4.z * QSC, v4.w * QSC));
    } else {
      float4 v4 = ((const float4*)W)[u - Qq * Dd / 4];
      ((uint2*)wb)[u - Qq * Dd / 4] =
          make_uint2(pk_bf(v4.x, v4.y), pk_bf(v4.z, v4.w));
    }
  }
}

// ---- K2: cross-attention, 512 thr/block, dbuf staging, LDS-P -------------
// grid 2*8*ns = [b][qtile 8 of 512 q][split ns]; block 512 = 8 waves x 64 q.
// 1 block/CU, 2 waves/SIMD. Dynamic LDS 96 KB:
//   buf0 X @0, Xt @16K; buf1 X @32K, Xt @48K; P @64K (8 waves x 4 KB).
__global__ __launch_bounds__(512, 2) void k_attn(
    const char* __restrict__ xn_t, const char* __restrict__ xnT_t,
    const unsigned short* __restrict__ qb,
    unsigned short* __restrict__ o_bf,       // [B][ns][Q][D] bf16
    float* __restrict__ l_part,              // [B][ns][Q]
    int ns_log2, int niter) {
  extern __shared__ __align__(16) char lds[];

  const int bid = blockIdx.x;
  const int ns = 1 << ns_log2;
  const int split = bid & (ns - 1);
  const int qt = (bid >> ns_log2) & 7;
  const int b = bid >> (ns_log2 + 3);
  const int tid = threadIdx.x;
  const int wave = tid >> 6, lane = tid & 63;
  const int col = lane & 31, half = lane >> 5;
  const int qwbase = qt * 512 + wave * 64;

  // Q B-fragments (prescaled bf16): frag[g*8+s], k = 16s+8h+j, n = g*32+col
  bf16x8 qf[16];
#pragma unroll
  for (int g = 0; g < 2; ++g)
#pragma unroll
    for (int s = 0; s < 8; ++s)
      qf[g * 8 + s] = *(const bf16x8*)(qb +
          (size_t)(qwbase + g * 32 + col) * Dd + s * 16 + half * 8);

  const floatx16 fz = {0.f,0.f,0.f,0.f,0.f,0.f,0.f,0.f,0.f,0.f,0.f,0.f,0.f,0.f,0.f,0.f};
  floatx16 O[8];
#pragma unroll
  for (int k = 0; k < 8; ++k) O[k] = fz;
  float ls0 = 0.f, ls1 = 0.f;

  const char* gx = xn_t + ((size_t)(b * 256 + split * niter)) * 16384;
  const char* gxt = xnT_t + ((size_t)(b * 256 + split * niter)) * 16384;
  char* pw = lds + 65536 + wave * 4096;
  const int lo16 = lane * 16;
  const int sa = wave * 2048;   // this wave's 2 KB slice within each 16 KB image

  // prologue: stage tile 0 into buf 0
  stage16(gx + sa + lo16, lds + sa);
  stage16(gx + sa + 1024 + lo16, lds + sa + 1024);
  stage16(gxt + sa + lo16, lds + 16384 + sa);
  stage16(gxt + sa + 1024 + lo16, lds + 16384 + sa + 1024);

  for (int i = 0; i < niter; ++i) {
    __syncthreads();   // buf[i&1] ready; its loads flew during previous compute
    if (i + 1 < niter) {
      char* nb = lds + ((i + 1) & 1) * 32768;
      const char* sx = gx + (size_t)(i + 1) * 16384;
      const char* st = gxt + (size_t)(i + 1) * 16384;
      stage16(sx + sa + lo16, nb + sa);
      stage16(sx + sa + 1024 + lo16, nb + sa + 1024);
      stage16(st + sa + lo16, nb + 16384 + sa);
      stage16(st + sa + 1024 + lo16, nb + 16384 + sa + 1024);
    }
    const char* ax_base = lds + (i & 1) * 32768;
    const char* bx_base = ax_base + 16384;

#pragma unroll
    for (int kb = 0; kb < 2; ++kb) {
      // S^T[32 kv][64 q] for this kv-half; ax shared by both q-groups
      floatx16 S0 = fz, S1 = fz;
#pragma unroll
      for (int s = 0; s < 8; ++s) {
        bf16x8 ax = *(const bf16x8*)(ax_base + kb * 8192 + s * 1024 + half * 512 + col * 16);
        S0 = __builtin_amdgcn_mfma_f32_32x32x16_bf16(ax, qf[s], S0, 0, 0, 0);
        S1 = __builtin_amdgcn_mfma_f32_32x32x16_bf16(ax, qf[8 + s], S1, 0, 0, 0);
      }
      // exp2 + l-sum; write P to per-wave LDS (in-wave DS order, no barrier)
#pragma unroll
      for (int t = 0; t < 4; ++t) {
        float a0 = fexp2(S0[4 * t]), a1 = fexp2(S0[4 * t + 1]);
        float a2 = fexp2(S0[4 * t + 2]), a3 = fexp2(S0[4 * t + 3]);
        float b0 = fexp2(S1[4 * t]), b1 = fexp2(S1[4 * t + 1]);
        float b2 = fexp2(S1[4 * t + 2]), b3 = fexp2(S1[4 * t + 3]);
        ls0 += (a0 + a1) + (a2 + a3);
        ls1 += (b0 + b1) + (b2 + b3);
        int ofs = t * 512 + col * 16 + half * 8;   // slab kvu=t, row q=col
        *(uint2*)(pw + ofs) = make_uint2(pk_bf(a0, a1), pk_bf(a2, a3));
        *(uint2*)(pw + 2048 + ofs) = make_uint2(pk_bf(b0, b1), pk_bf(b2, b3));
      }
      // O[64 q][128 d] += P . Xt ; bx shared across q-groups
#pragma unroll
      for (int s2l = 0; s2l < 2; ++s2l) {
        bf16x8 ap0 = *(const bf16x8*)(pw + s2l * 1024 + half * 512 + col * 16);
        bf16x8 ap1 = *(const bf16x8*)(pw + 2048 + s2l * 1024 + half * 512 + col * 16);
        const int s2 = 2 * kb + s2l;
#pragma unroll
        for (int dn = 0; dn < 4; ++dn) {
          bf16x8 bx = *(const bf16x8*)(bx_base + dn * 4096 + s2 * 1024 + half * 512 + col * 16);
          O[dn] = __builtin_amdgcn_mfma_f32_32x32x16_bf16(ap0, bx, O[dn], 0, 0, 0);
          O[4 + dn] = __builtin_amdgcn_mfma_f32_32x32x16_bf16(ap1, bx, O[4 + dn], 0, 0, 0);
        }
      }
    }
  }

  // epilogue
  float lt0 = ls0 + __shfl_xor(ls0, 32);
  float lt1 = ls1 + __shfl_xor(ls1, 32);
  if (half == 0) {
    size_t lb = ((size_t)(b * ns + split)) * Qq + qwbase;
    l_part[lb + col] = lt0;
    l_part[lb + 32 + col] = lt1;
  }
  unsigned short* ob = o_bf + (((size_t)(b * ns + split)) * Qq + qwbase) * Dd;
#pragma unroll
  for (int g = 0; g < 2; ++g)
#pragma unroll
    for (int dn = 0; dn < 4; ++dn)
#pragma unroll
      for (int r = 0; r < 16; ++r) {
        int q = g * 32 + (r & 3) + 8 * (r >> 2) + 4 * half;
        ob[(size_t)q * Dd + dn * 32 + col] = bf1(O[g * 4 + dn][r]);
      }
}

// ---- K3: combine bf16 splits, normalize, trailing GEMM -------------------
// grid 256 = [b 2][qchunk 128 of 32 q]; block 256 = 4 waves (wave owns 64 E)
__global__ __launch_bounds__(256) void k_comb(
    const unsigned short* __restrict__ o_bf, const float* __restrict__ l_part,
    const unsigned short* __restrict__ wb, float* __restrict__ out, int ns) {
  __shared__ __align__(16) char lds_a[8192];   // [32 q][16 du], q^(du&7) swizzle
  __shared__ float lds_linv[32];
  const int bid = blockIdx.x;
  const int b = bid >> 7, qc = bid & 127;
  const int qbase = qc * 32;
  const int tid = threadIdx.x;
  const int wave = tid >> 6, lane = tid & 63;
  const int col = lane & 31, half = lane >> 5;

  if (tid < 32) {
    float l = 0.f;
    for (int s = 0; s < ns; ++s)
      l += l_part[(size_t)(b * ns + s) * Qq + qbase + tid];
    lds_linv[tid] = 1.0f / l;
  }
  __syncthreads();

#pragma unroll
  for (int i = 0; i < 4; ++i) {
    int idx = i * 256 + tid;      // 1024 units of 4 d: q = idx>>5, d4 = idx&31
    int q = idx >> 5, d4 = idx & 31;
    float a0 = 0.f, a1 = 0.f, a2 = 0.f, a3 = 0.f;
    for (int s = 0; s < ns; ++s) {
      uint2 v = *(const uint2*)(o_bf +
          ((size_t)(b * ns + s) * Qq + qbase + q) * Dd + d4 * 4);
      a0 += __uint_as_float(v.x << 16);
      a1 += __uint_as_float(v.x & 0xffff0000u);
      a2 += __uint_as_float(v.y << 16);
      a3 += __uint_as_float(v.y & 0xffff0000u);
    }
    float li = lds_linv[q];
    int du = d4 >> 1;
    int pos = (du >> 1) * 1024 + (du & 1) * 512 + ((q ^ (du & 7)) & 31) * 16 + (d4 & 1) * 8;
    *(uint2*)(lds_a + pos) =
        make_uint2(pk_bf(a0 * li, a1 * li), pk_bf(a2 * li, a3 * li));
  }
  __syncthreads();

  bf16x8 af[8];
#pragma unroll
  for (int s = 0; s < 8; ++s) {
    int du = 2 * s + half;
    af[s] = *(const bf16x8*)(lds_a + s * 1024 + half * 512 + ((col ^ (du & 7)) & 31) * 16);
  }

  const floatx16 fz = {0.f,0.f,0.f,0.f,0.f,0.f,0.f,0.f,0.f,0.f,0.f,0.f,0.f,0.f,0.f,0.f};
#pragma unroll
  for (int et = 0; et < 2; ++et) {
    floatx16 C = fz;
    int e_row = wave * 64 + et * 32 + col;
#pragma unroll
    for (int s = 0; s < 8; ++s) {
      bf16x8 bw = *(const bf16x8*)(wb + (size_t)e_row * Dd + s * 16 + half * 8);
      C = __builtin_amdgcn_mfma_f32_32x32x16_bf16(af[s], bw, C, 0, 0, 0);
    }
#pragma unroll
    for (int r = 0; r < 16; ++r) {
      int q = qbase + (r & 3) + 8 * (r >> 2) + 4 * half;
      out[((size_t)b * Qq + q) * Ee + wave * 64 + et * 32 + col] = C[r];
    }
  }
}

// ---- launcher ------------------------------------------------------------
extern "C" void kernel_launch(void* const* d_in, const int* in_sizes, int n_in,
                              void* d_out, int out_size, void* d_ws, size_t ws_size,
                              hipStream_t stream) {
  const float* x = (const float*)d_in[0];
  const float* gamma = (const float*)d_in[1];
  const float* beta = (const float*)d_in[2];
  const float* queries = (const float*)d_in[3];
  const float* W = (const float*)d_in[4];
  float* out = (float*)d_out;

  char* w = (char*)d_ws;
  char* xn_t = w;                                     // 8 MB
  char* xnT_t = w + 8388608;                          // 8 MB
  unsigned short* qb = (unsigned short*)(w + 16777216);   // 1 MB
  unsigned short* wb = (unsigned short*)(w + 17825792);   // 64 KB
  unsigned short* o_bf = (unsigned short*)(w + 17891328); // 2*ns*Q*D*2

  const size_t base = 17891328;
  const size_t need16 = base + (size_t)2 * 16 * Qq * Dd * 2 + (size_t)2 * 16 * Qq * 4;
  int ns_log2 = (ws_size >= need16) ? 4 : 3;
  int ns = 1 << ns_log2;
  int niter = 256 / ns;
  float* l_part = (float*)(w + base + (size_t)2 * ns * Qq * Dd * 2);

  static bool attr_set = false;
  if (!attr_set) {
    hipFuncSetAttribute((const void*)k_attn,
                        hipFuncAttributeMaxDynamicSharedMemorySize, 98304);
    attr_set = true;
  }

  k_lnt<<<dim3(512), dim3(256), 0, stream>>>(x, gamma, beta, queries, W,
                                             xn_t, xnT_t, qb, wb);
  k_attn<<<dim3(2 * 8 * ns), dim3(512), 98304, stream>>>(xn_t, xnT_t, qb,
                                                         o_bf, l_part, ns_log2, niter);
  k_comb<<<dim3(256), dim3(256), 0, stream>>>(o_bf, l_part, wb, out, ns);
}